// Round 1
// baseline (133.383 us; speedup 1.0000x reference)
//
#include <hip/hip_runtime.h>

#define TPB 256
#define SPLIT 16

// ---------------------------------------------------------------------------
// Init the per-point running-min arrays (uint bit patterns of non-negative
// floats; uint compare == float compare for values >= 0).
// min1 (pred->target): big sentinel. min2 (target->pred): exactly 1e10f so an
// all-invalid batch reproduces the reference's BIG value.
// ---------------------------------------------------------------------------
__global__ void __launch_bounds__(TPB) init_mins(unsigned int* w, int n1, int n2) {
    int i = blockIdx.x * blockDim.x + threadIdx.x;
    if (i < n1) {
        w[i] = __float_as_uint(3.0e38f);
    } else if (i < n1 + n2) {
        w[i] = __float_as_uint(1.0e10f);
    }
}

// ---------------------------------------------------------------------------
// Generic directed nearest-neighbor min.
//   Apts : B x NA x 3  query points (one per thread, held in registers)
//   Bpts : B x NB x 3  database points (staged through LDS as float4)
//   labelB: validity for database points (nullptr => all valid)
//   outmin: B x NA running min of squared distance (uint bits, atomicMin)
// Validity / padding handled via w-sentinel: d = max(dist2, w); w = 0 for
// valid points, 1e10 for invalid/pad -> exactly matches reference semantics
// (jnp.where(mask, d, 1e10)) and also subsumes the max(d, 0) clamp.
// grid = (B * natiles, SPLIT); block owns TPB query points and scans the
// blockIdx.y-th slice of the database.
// ---------------------------------------------------------------------------
__global__ void __launch_bounds__(TPB) nn_min_kernel(
    const float* __restrict__ Apts,
    const float* __restrict__ Bpts,
    const int*   __restrict__ labelB,
    unsigned int* __restrict__ outmin,
    int NA, int NB, int natiles)
{
    __shared__ float4 tile[TPB];

    int b  = blockIdx.x / natiles;
    int at = blockIdx.x - b * natiles;
    int a  = at * TPB + threadIdx.x;
    bool a_valid = (a < NA);

    size_t abase = (size_t)b * NA;
    size_t ai    = (abase + (a_valid ? a : 0)) * 3;
    float px = Apts[ai + 0];
    float py = Apts[ai + 1];
    float pz = Apts[ai + 2];

    int slen = (NB + SPLIT - 1) / SPLIT;
    int sbeg = blockIdx.y * slen;
    int send = min(sbeg + slen, NB);
    size_t bbase = (size_t)b * NB;

    float best = 3.0e38f;

    for (int c = sbeg; c < send; c += TPB) {
        int m = c + threadIdx.x;
        float4 q = make_float4(0.0f, 0.0f, 0.0f, 1.0e10f); // pad sentinel
        if (m < send) {
            const float* src = Bpts + (bbase + m) * 3;
            q.x = src[0];
            q.y = src[1];
            q.z = src[2];
            q.w = (labelB == nullptr || labelB[bbase + m] == 1) ? 0.0f : 1.0e10f;
        }
        __syncthreads();              // protect previous iteration's reads
        tile[threadIdx.x] = q;
        __syncthreads();

#pragma unroll 8
        for (int j = 0; j < TPB; ++j) {
            float4 t = tile[j];       // wave-uniform address -> LDS broadcast
            float dx = px - t.x;
            float dy = py - t.y;
            float dz = pz - t.z;
            float d = fmaf(dx, dx, fmaf(dy, dy, dz * dz));
            d = fmaxf(d, t.w);        // validity / pad / clamp in one op
            best = fminf(best, d);
        }
    }

    if (a_valid) {
        atomicMin(&outmin[abase + a], __float_as_uint(best));
    }
}

// ---------------------------------------------------------------------------
// Finalize: per-batch masked means + scalar output. Single block, fully
// deterministic.
// ---------------------------------------------------------------------------
__device__ float block_reduce_sum(float v, float* red) {
    int tid = threadIdx.x;
    red[tid] = v;
    __syncthreads();
    for (int s = TPB / 2; s > 0; s >>= 1) {
        if (tid < s) red[tid] += red[tid + s];
        __syncthreads();
    }
    float r = red[0];
    __syncthreads();
    return r;
}

__global__ void __launch_bounds__(TPB) finalize_kernel(
    const unsigned int* __restrict__ min1,
    const unsigned int* __restrict__ min2,
    const int* __restrict__ label,
    float* __restrict__ out,
    int B, int N, int M)
{
    __shared__ float red[TPB];
    int tid = threadIdx.x;
    float acc = 0.0f;

    for (int b = 0; b < B; ++b) {
        float s1 = 0.0f, c1 = 0.0f, s2 = 0.0f;
        size_t nb = (size_t)b * N;
        size_t mb = (size_t)b * M;
        for (int n = tid; n < N; n += TPB) {
            if (label[nb + n] == 1) {
                s1 += sqrtf(__uint_as_float(min1[nb + n]));
                c1 += 1.0f;
            }
        }
        for (int m = tid; m < M; m += TPB) {
            s2 += sqrtf(__uint_as_float(min2[mb + m]));
        }
        s1 = block_reduce_sum(s1, red);
        c1 = block_reduce_sum(c1, red);
        s2 = block_reduce_sum(s2, red);
        float m1 = s1 / fmaxf(c1, 1.0f);
        float m2 = s2 / (float)M;
        acc += 0.5f * (m1 + m2);
    }

    if (tid == 0) {
        out[0] = acc / (float)B;   // * LOSS_WEIGHT (== 1.0)
    }
}

// ---------------------------------------------------------------------------
extern "C" void kernel_launch(void* const* d_in, const int* in_sizes, int n_in,
                              void* d_out, int out_size, void* d_ws, size_t ws_size,
                              hipStream_t stream) {
    const float* pred   = (const float*)d_in[0];  // B*N*3 f32
    const float* target = (const float*)d_in[1];  // B*M*3 f32
    const int*   label  = (const int*)  d_in[2];  // B*N   i32

    int B = in_sizes[3];                 // nums has shape (B,)
    int N = in_sizes[2] / B;             // label is B*N
    int M = in_sizes[1] / (3 * B);       // target is B*M*3

    unsigned int* min1 = (unsigned int*)d_ws;            // B*N
    unsigned int* min2 = min1 + (size_t)B * N;           // B*M

    int total = B * (N + M);
    init_mins<<<(total + TPB - 1) / TPB, TPB, 0, stream>>>(min1, B * N, B * M);

    int ntiles = (N + TPB - 1) / TPB;
    int mtiles = (M + TPB - 1) / TPB;

    // pred -> target: query = pred, database = target (all valid)
    dim3 g1(B * ntiles, SPLIT);
    nn_min_kernel<<<g1, TPB, 0, stream>>>(pred, target, nullptr, min1, N, M, ntiles);

    // target -> pred: query = target, database = pred (masked by label)
    dim3 g2(B * mtiles, SPLIT);
    nn_min_kernel<<<g2, TPB, 0, stream>>>(target, pred, label, min2, M, N, mtiles);

    finalize_kernel<<<1, TPB, 0, stream>>>(min1, min2, label, (float*)d_out, B, N, M);
}

// Round 2
// 37.397 us; speedup vs baseline: 3.5667x; 3.5667x over previous
//
#include <hip/hip_runtime.h>

#define TPB   256
#define QPT   4      // query points per thread (registers)
#define SPLIT 16     // database slices per direction (4096/16 = 256 = one tile)

#define POISON 1.0e5f   // poisoned coordinate -> d ~ 1e10, matches ref BIG scale

// ---------------------------------------------------------------------------
// Seed per-point running-min arrays (uint bit patterns of non-negative floats;
// uint compare == float compare for values >= 0).
// min1 (pred->target): big sentinel (always overwritten).
// min2 (target->pred): exactly 1e10 so an all-invalid batch matches reference.
// ---------------------------------------------------------------------------
__global__ void __launch_bounds__(TPB) init_mins(unsigned int* w, int n1, int n2) {
    int i = blockIdx.x * blockDim.x + threadIdx.x;
    if (i < n1) {
        w[i] = __float_as_uint(3.0e38f);
    } else if (i < n1 + n2) {
        w[i] = __float_as_uint(1.0e10f);
    }
}

// ---------------------------------------------------------------------------
// Fused directed nearest-neighbor min, both directions in one launch.
//   blockIdx.z = 0 : query = pred  (NA=N), database = target (NB=M), all valid
//   blockIdx.z = 1 : query = target(NA=M), database = pred   (NB=N), label-masked
// Each thread holds QPT query points in registers; database points staged in
// LDS as float4 (one ds_read_b128 broadcast feeds QPT*7 VALU ops).
// Invalid / pad database points are coordinate-poisoned (x=POISON) so their
// distance ~1e10 — no per-pair mask op needed.
// grid = (B * natmax, SPLIT, 2).
// ---------------------------------------------------------------------------
__global__ void __launch_bounds__(TPB) nn_fused(
    const float* __restrict__ pred,
    const float* __restrict__ target,
    const int*   __restrict__ label,
    unsigned int* __restrict__ min1,
    unsigned int* __restrict__ min2,
    int N, int M, int natmax)
{
    __shared__ float4 tile[TPB];

    const int dir = blockIdx.z;
    const float* __restrict__ A  = dir ? target : pred;
    const float* __restrict__ Bp = dir ? pred   : target;
    const int NA = dir ? M : N;
    const int NB = dir ? N : M;
    const int* __restrict__ labB = dir ? label : nullptr;
    unsigned int* __restrict__ outm = dir ? min2 : min1;

    const int natiles = (NA + TPB * QPT - 1) / (TPB * QPT);
    const int b  = blockIdx.x / natmax;
    const int at = blockIdx.x - b * natmax;
    if (at >= natiles) return;

    const size_t abase = (size_t)b * NA;

    float px[QPT], py[QPT], pz[QPT], best[QPT];
#pragma unroll
    for (int q = 0; q < QPT; ++q) {
        int a = at * (TPB * QPT) + q * TPB + threadIdx.x;
        int idx = (a < NA) ? a : 0;
        const float* sp = A + (abase + idx) * 3;
        px[q] = sp[0];
        py[q] = sp[1];
        pz[q] = sp[2];
        best[q] = 3.0e38f;
    }

    const int slen = (NB + SPLIT - 1) / SPLIT;
    const int sbeg = blockIdx.y * slen;
    const int send = min(sbeg + slen, NB);
    const size_t bbase = (size_t)b * NB;

    for (int c = sbeg; c < send; c += TPB) {
        int m = c + threadIdx.x;
        float4 qv = make_float4(POISON, 0.0f, 0.0f, 0.0f);   // pad sentinel
        if (m < send) {
            const float* sp = Bp + (bbase + m) * 3;
            float x = sp[0], y = sp[1], z = sp[2];
            if (labB != nullptr && labB[bbase + m] != 1) x = POISON;  // invalid
            qv = make_float4(x, y, z, 0.0f);
        }
        __syncthreads();              // protect previous iteration's reads
        tile[threadIdx.x] = qv;
        __syncthreads();

        const int jn = min(send - c, TPB);
        if (jn == TPB) {
#pragma unroll 16
            for (int j = 0; j < TPB; ++j) {
                float4 t = tile[j];   // wave-uniform -> LDS broadcast
#pragma unroll
                for (int q = 0; q < QPT; ++q) {
                    float dx = px[q] - t.x;
                    float dy = py[q] - t.y;
                    float dz = pz[q] - t.z;
                    float d = fmaf(dx, dx, fmaf(dy, dy, dz * dz));
                    best[q] = fminf(best[q], d);
                }
            }
        } else {
            for (int j = 0; j < jn; ++j) {
                float4 t = tile[j];
#pragma unroll
                for (int q = 0; q < QPT; ++q) {
                    float dx = px[q] - t.x;
                    float dy = py[q] - t.y;
                    float dz = pz[q] - t.z;
                    float d = fmaf(dx, dx, fmaf(dy, dy, dz * dz));
                    best[q] = fminf(best[q], d);
                }
            }
        }
    }

#pragma unroll
    for (int q = 0; q < QPT; ++q) {
        int a = at * (TPB * QPT) + q * TPB + threadIdx.x;
        if (a < NA) {
            atomicMin(&outm[abase + a], __float_as_uint(best[q]));
        }
    }
}

// ---------------------------------------------------------------------------
// Stage A reduction: each block reduces one 256-element tile of min1 (masked
// sqrt-sum + count) or min2 (sqrt-sum), writing one partial per block.
// ---------------------------------------------------------------------------
__device__ float block_reduce_sum(float v, float* red) {
    int tid = threadIdx.x;
    red[tid] = v;
    __syncthreads();
    for (int s = TPB / 2; s > 0; s >>= 1) {
        if (tid < s) red[tid] += red[tid + s];
        __syncthreads();
    }
    float r = red[0];
    __syncthreads();
    return r;
}

__global__ void __launch_bounds__(TPB) partial_kernel(
    const unsigned int* __restrict__ min1,
    const unsigned int* __restrict__ min2,
    const int* __restrict__ label,
    float* __restrict__ s1, float* __restrict__ c1, float* __restrict__ s2,
    int B, int N, int M, int ptN, int ptM)
{
    __shared__ float red[TPB];
    const int r = blockIdx.x;
    const int regionN = B * ptN;

    if (r < regionN) {
        int b = r / ptN;
        int t = r - b * ptN;
        int n = t * TPB + threadIdx.x;
        float s = 0.0f, cc = 0.0f;
        if (n < N) {
            size_t i = (size_t)b * N + n;
            if (label[i] == 1) {
                s = sqrtf(__uint_as_float(min1[i]));
                cc = 1.0f;
            }
        }
        s  = block_reduce_sum(s, red);
        cc = block_reduce_sum(cc, red);
        if (threadIdx.x == 0) { s1[r] = s; c1[r] = cc; }
    } else {
        int r2 = r - regionN;
        int b = r2 / ptM;
        int t = r2 - b * ptM;
        int m = t * TPB + threadIdx.x;
        float s = 0.0f;
        if (m < M) {
            s = sqrtf(__uint_as_float(min2[(size_t)b * M + m]));
        }
        s = block_reduce_sum(s, red);
        if (threadIdx.x == 0) s2[r2] = s;
    }
}

// ---------------------------------------------------------------------------
// Stage B: tiny deterministic final combine (one block, 64 threads).
// ---------------------------------------------------------------------------
__global__ void __launch_bounds__(64) final_kernel(
    const float* __restrict__ s1, const float* __restrict__ c1,
    const float* __restrict__ s2,
    float* __restrict__ out, int B, int M, int ptN, int ptM)
{
    __shared__ float acc[64];
    int tid = threadIdx.x;
    float v = 0.0f;
    if (tid < B) {
        float S1 = 0.0f, C1 = 0.0f, S2 = 0.0f;
        for (int i = 0; i < ptN; ++i) { S1 += s1[tid * ptN + i]; C1 += c1[tid * ptN + i]; }
        for (int i = 0; i < ptM; ++i) { S2 += s2[tid * ptM + i]; }
        float m1 = S1 / fmaxf(C1, 1.0f);
        float m2 = S2 / (float)M;
        v = 0.5f * (m1 + m2);
    }
    acc[tid] = v;
    __syncthreads();
    if (tid == 0) {
        float a = 0.0f;
        for (int b = 0; b < B; ++b) a += acc[b];
        out[0] = a / (float)B;   // * LOSS_WEIGHT (== 1.0)
    }
}

// ---------------------------------------------------------------------------
extern "C" void kernel_launch(void* const* d_in, const int* in_sizes, int n_in,
                              void* d_out, int out_size, void* d_ws, size_t ws_size,
                              hipStream_t stream) {
    const float* pred   = (const float*)d_in[0];  // B*N*3 f32
    const float* target = (const float*)d_in[1];  // B*M*3 f32
    const int*   label  = (const int*)  d_in[2];  // B*N   i32

    const int B = in_sizes[3];                 // nums has shape (B,)
    const int N = in_sizes[2] / B;             // label is B*N
    const int M = in_sizes[1] / (3 * B);       // target is B*M*3

    // workspace layout
    unsigned int* min1 = (unsigned int*)d_ws;            // B*N
    unsigned int* min2 = min1 + (size_t)B * N;           // B*M
    const int ptN = (N + TPB - 1) / TPB;
    const int ptM = (M + TPB - 1) / TPB;
    float* s1 = (float*)(min2 + (size_t)B * M);          // B*ptN
    float* c1 = s1 + (size_t)B * ptN;                    // B*ptN
    float* s2 = c1 + (size_t)B * ptN;                    // B*ptM

    const int total = B * (N + M);
    init_mins<<<(total + TPB - 1) / TPB, TPB, 0, stream>>>(min1, B * N, B * M);

    const int nat1 = (N + TPB * QPT - 1) / (TPB * QPT);
    const int nat2 = (M + TPB * QPT - 1) / (TPB * QPT);
    const int natmax = max(nat1, nat2);
    dim3 g(B * natmax, SPLIT, 2);
    nn_fused<<<g, TPB, 0, stream>>>(pred, target, label, min1, min2, N, M, natmax);

    const int nred = B * (ptN + ptM);
    partial_kernel<<<nred, TPB, 0, stream>>>(min1, min2, label, s1, c1, s2,
                                             B, N, M, ptN, ptM);

    final_kernel<<<1, 64, 0, stream>>>(s1, c1, s2, (float*)d_out, B, M, ptN, ptM);
}

// Round 3
// 35.581 us; speedup vs baseline: 3.7488x; 1.0511x over previous
//
#include <hip/hip_runtime.h>

#define TPB   128    // threads per nn block (2 waves)
#define QPT   8      // query points per thread (registers)
#define SPLIT 32     // database slices per direction (4096/32 = 128 = one stage)
#define RTPB  256    // reduction threads per block

// ---------------------------------------------------------------------------
// Directed nearest-neighbor min, both directions in one launch.
//   blockIdx.z = 0 : query = pred  (NA=N), database = target (NB=M), all valid
//   blockIdx.z = 1 : query = target(NA=M), database = pred   (NB=N), label-mask
// Expanded distance: d = |p|^2 + |t|^2 - 2 p.t.  We min over (tn - 2 p.t)
// (monotone shift by pn), add pn once per query at the end, clamp >= 0.
// Invalid / pad database points: coords=0, tn=1e10 -> candidate = pn + 1e10,
// matching the reference's BIG mask to ~1e-9 relative.
// Each (tile, split) block writes its QPT*TPB mins to a private minsplit slot:
// no atomics, no init pass, bit-deterministic.
// grid = (B * natmax, SPLIT, 2).
// ---------------------------------------------------------------------------
__global__ void __launch_bounds__(TPB) nn_kernel(
    const float* __restrict__ pred,
    const float* __restrict__ target,
    const int*   __restrict__ label,
    float* __restrict__ minsplit,     // [2][B][SPLIT][stride]
    int B, int N, int M, int natmax, int stride)
{
    __shared__ float4 tile[TPB];

    const int dir = blockIdx.z;
    const float* __restrict__ A  = dir ? target : pred;
    const float* __restrict__ Bp = dir ? pred   : target;
    const int NA = dir ? M : N;
    const int NB = dir ? N : M;
    const int* __restrict__ labB = dir ? label : nullptr;

    const int natiles = (NA + TPB * QPT - 1) / (TPB * QPT);
    const int b  = blockIdx.x / natmax;
    const int at = blockIdx.x - b * natmax;
    if (at >= natiles) return;

    const size_t abase = (size_t)b * NA;

    float px[QPT], py[QPT], pz[QPT], pn[QPT], best[QPT];
#pragma unroll
    for (int q = 0; q < QPT; ++q) {
        int a = at * (TPB * QPT) + q * TPB + threadIdx.x;
        int idx = (a < NA) ? a : 0;
        const float* sp = A + (abase + idx) * 3;
        px[q] = sp[0];
        py[q] = sp[1];
        pz[q] = sp[2];
        pn[q] = fmaf(px[q], px[q], fmaf(py[q], py[q], pz[q] * pz[q]));
        best[q] = 3.0e38f;
    }

    const int slen = (NB + SPLIT - 1) / SPLIT;
    const int sbeg = blockIdx.y * slen;
    const int send = min(sbeg + slen, NB);
    const size_t bbase = (size_t)b * NB;

    for (int c = sbeg; c < send; c += TPB) {
        int m = c + threadIdx.x;
        float4 qv = make_float4(0.0f, 0.0f, 0.0f, 1.0e10f);  // pad sentinel
        if (m < send) {
            const float* sp = Bp + (bbase + m) * 3;
            float x = sp[0], y = sp[1], z = sp[2];
            float tn = fmaf(x, x, fmaf(y, y, z * z));
            if (labB != nullptr && labB[bbase + m] != 1) {    // invalid point
                x = 0.0f; y = 0.0f; z = 0.0f; tn = 1.0e10f;
            }
            qv = make_float4(x, y, z, tn);
        }
        __syncthreads();              // protect previous iteration's reads
        tile[threadIdx.x] = qv;
        __syncthreads();

        const int jn = min(send - c, TPB);
        const int jeven = jn & ~1;
#pragma unroll 8
        for (int j = 0; j < jeven; j += 2) {
            float4 t0 = tile[j];      // wave-uniform -> LDS broadcast
            float4 t1 = tile[j + 1];
#pragma unroll
            for (int q = 0; q < QPT; ++q) {
                float s0 = fmaf(px[q], t0.x, fmaf(py[q], t0.y, pz[q] * t0.z));
                float s1 = fmaf(px[q], t1.x, fmaf(py[q], t1.y, pz[q] * t1.z));
                float v0 = fmaf(-2.0f, s0, t0.w);
                float v1 = fmaf(-2.0f, s1, t1.w);
                best[q] = fminf(best[q], fminf(v0, v1));   // -> v_min3_f32
            }
        }
        if (jn & 1) {
            float4 t0 = tile[jn - 1];
#pragma unroll
            for (int q = 0; q < QPT; ++q) {
                float s0 = fmaf(px[q], t0.x, fmaf(py[q], t0.y, pz[q] * t0.z));
                best[q] = fminf(best[q], fmaf(-2.0f, s0, t0.w));
            }
        }
    }

    float* out = minsplit + (((size_t)dir * B + b) * SPLIT + blockIdx.y) * stride;
#pragma unroll
    for (int q = 0; q < QPT; ++q) {
        int a = at * (TPB * QPT) + q * TPB + threadIdx.x;
        if (a < NA) {
            out[a] = fmaxf(best[q] + pn[q], 0.0f);
        }
    }
}

// ---------------------------------------------------------------------------
// Stage A: per-query min over SPLIT slices, sqrt, masked block-level sums.
// One partial triple per block, fixed-order reduction -> deterministic.
// ---------------------------------------------------------------------------
__device__ float block_reduce_sum(float v, float* red) {
    int tid = threadIdx.x;
    red[tid] = v;
    __syncthreads();
    for (int s = RTPB / 2; s > 0; s >>= 1) {
        if (tid < s) red[tid] += red[tid + s];
        __syncthreads();
    }
    float r = red[0];
    __syncthreads();
    return r;
}

__global__ void __launch_bounds__(RTPB) partial_kernel(
    const float* __restrict__ minsplit,
    const int* __restrict__ label,
    float* __restrict__ s1, float* __restrict__ c1, float* __restrict__ s2,
    int B, int N, int M, int ptN, int ptM, int stride)
{
    __shared__ float red[RTPB];
    const int r = blockIdx.x;
    const int regionN = B * ptN;

    if (r < regionN) {                       // dir 0: pred -> target (masked)
        int b = r / ptN;
        int t = r - b * ptN;
        int n = t * RTPB + threadIdx.x;
        float s = 0.0f, cc = 0.0f;
        if (n < N) {
            const float* base = minsplit + ((size_t)b * SPLIT) * stride + n;
            float m = base[0];
            for (int sp = 1; sp < SPLIT; ++sp) {
                m = fminf(m, base[(size_t)sp * stride]);
            }
            if (label[(size_t)b * N + n] == 1) {
                s = sqrtf(m);
                cc = 1.0f;
            }
        }
        s  = block_reduce_sum(s, red);
        cc = block_reduce_sum(cc, red);
        if (threadIdx.x == 0) { s1[r] = s; c1[r] = cc; }
    } else {                                 // dir 1: target -> pred (mean)
        int r2 = r - regionN;
        int b = r2 / ptM;
        int t = r2 - b * ptM;
        int mq = t * RTPB + threadIdx.x;
        float s = 0.0f;
        if (mq < M) {
            const float* base = minsplit + (((size_t)B + b) * SPLIT) * stride + mq;
            float m = base[0];
            for (int sp = 1; sp < SPLIT; ++sp) {
                m = fminf(m, base[(size_t)sp * stride]);
            }
            s = sqrtf(m);
        }
        s = block_reduce_sum(s, red);
        if (threadIdx.x == 0) s2[r2] = s;
    }
}

// ---------------------------------------------------------------------------
// Stage B: tiny deterministic final combine (one block, 64 threads).
// ---------------------------------------------------------------------------
__global__ void __launch_bounds__(64) final_kernel(
    const float* __restrict__ s1, const float* __restrict__ c1,
    const float* __restrict__ s2,
    float* __restrict__ out, int B, int M, int ptN, int ptM)
{
    __shared__ float acc[64];
    int tid = threadIdx.x;
    float v = 0.0f;
    if (tid < B) {
        float S1 = 0.0f, C1 = 0.0f, S2 = 0.0f;
        for (int i = 0; i < ptN; ++i) { S1 += s1[tid * ptN + i]; C1 += c1[tid * ptN + i]; }
        for (int i = 0; i < ptM; ++i) { S2 += s2[tid * ptM + i]; }
        float m1 = S1 / fmaxf(C1, 1.0f);
        float m2 = S2 / (float)M;
        v = 0.5f * (m1 + m2);
    }
    acc[tid] = v;
    __syncthreads();
    if (tid == 0) {
        float a = 0.0f;
        for (int b = 0; b < B; ++b) a += acc[b];
        out[0] = a / (float)B;   // * LOSS_WEIGHT (== 1.0)
    }
}

// ---------------------------------------------------------------------------
extern "C" void kernel_launch(void* const* d_in, const int* in_sizes, int n_in,
                              void* d_out, int out_size, void* d_ws, size_t ws_size,
                              hipStream_t stream) {
    const float* pred   = (const float*)d_in[0];  // B*N*3 f32
    const float* target = (const float*)d_in[1];  // B*M*3 f32
    const int*   label  = (const int*)  d_in[2];  // B*N   i32

    const int B = in_sizes[3];                 // nums has shape (B,)
    const int N = in_sizes[2] / B;             // label is B*N
    const int M = in_sizes[1] / (3 * B);       // target is B*M*3

    const int stride = (N > M) ? N : M;

    // workspace layout (ws is ~256 MiB; we use ~4.2 MiB)
    float* minsplit = (float*)d_ws;                              // 2*B*SPLIT*stride
    const int ptN = (N + RTPB - 1) / RTPB;
    const int ptM = (M + RTPB - 1) / RTPB;
    float* s1 = minsplit + (size_t)2 * B * SPLIT * stride;       // B*ptN
    float* c1 = s1 + (size_t)B * ptN;                            // B*ptN
    float* s2 = c1 + (size_t)B * ptN;                            // B*ptM

    const int nat1 = (N + TPB * QPT - 1) / (TPB * QPT);
    const int nat2 = (M + TPB * QPT - 1) / (TPB * QPT);
    const int natmax = (nat1 > nat2) ? nat1 : nat2;
    dim3 g(B * natmax, SPLIT, 2);
    nn_kernel<<<g, TPB, 0, stream>>>(pred, target, label, minsplit,
                                     B, N, M, natmax, stride);

    const int nred = B * (ptN + ptM);
    partial_kernel<<<nred, RTPB, 0, stream>>>(minsplit, label, s1, c1, s2,
                                              B, N, M, ptN, ptM, stride);

    final_kernel<<<1, 64, 0, stream>>>(s1, c1, s2, (float*)d_out, B, M, ptN, ptM);
}